// Round 6
// baseline (228.209 us; speedup 1.0000x reference)
//
#include <hip/hip_runtime.h>

#define HEADS 16
#define DH    64
#define EMB   1024
#define NBAT  2
#define SEQ   2048
#define KDIM  1024
#define NROW  (NBAT * SEQ)     // 4096 rows in projection GEMM

typedef __attribute__((ext_vector_type(8))) short short8;   // 8 bf16 MFMA A/B frag
typedef __attribute__((ext_vector_type(4))) short short4v;  // 4 bf16 (8B packed store)
typedef __attribute__((ext_vector_type(4))) float floatx4;  // MFMA C/D frag
typedef unsigned short u16;
typedef unsigned int   u32;
typedef unsigned long long u64;

__device__ __forceinline__ u16 f2bf(float x) {          // fp32 -> bf16 RNE
    u32 u = __builtin_bit_cast(u32, x);
    u += 0x7fffu + ((u >> 16) & 1u);
    return (u16)(u >> 16);
}
__device__ __forceinline__ float bf2f(u16 v) {
    return __builtin_bit_cast(float, ((u32)v) << 16);
}
// pack two fp32 -> two bf16 (truncation) in ONE v_perm_b32
__device__ __forceinline__ u32 pack_bf16_trunc(float lo, float hi) {
    return __builtin_amdgcn_perm(__builtin_bit_cast(u32, hi),
                                 __builtin_bit_cast(u32, lo), 0x07060302u);
}

// async global->LDS, 16B per lane; LDS dest is wave-uniform base + lane*16
__device__ __forceinline__ void gll16(const u16* g, u16* l) {
    __builtin_amdgcn_global_load_lds((const __attribute__((address_space(1))) u32*)g,
                                     (__attribute__((address_space(3))) u32*)l, 16, 0, 0);
}

// ---------------------------------------------------------------------------
// fp32 -> bf16 pre-convert of X (q,k,v: 4M elems each) and W (wq,wk,wv: 1M each)
// ---------------------------------------------------------------------------
__global__ __launch_bounds__(256) void cvt_kernel(
    const float* __restrict__ q, const float* __restrict__ k, const float* __restrict__ v,
    const float* __restrict__ wq, const float* __restrict__ wk, const float* __restrict__ wv,
    u16* __restrict__ xb, u16* __restrict__ wb)
{
    const int z = blockIdx.y;
    const float* src; u16* dst; int n;
    if (z < 3) { src = (z == 0) ? q : (z == 1) ? k : v;     dst = xb + (size_t)z * 4194304;       n = 4194304; }
    else       { src = (z == 3) ? wq : (z == 4) ? wk : wv;  dst = wb + (size_t)(z - 3) * 1048576; n = 1048576; }
    for (int i = (blockIdx.x * 256 + threadIdx.x) * 8; i < n; i += 512 * 256 * 8) {
        float4 a = *(const float4*)(src + i);
        float4 b = *(const float4*)(src + i + 4);
        short8 o;
        o[0] = (short)f2bf(a.x); o[1] = (short)f2bf(a.y); o[2] = (short)f2bf(a.z); o[3] = (short)f2bf(a.w);
        o[4] = (short)f2bf(b.x); o[5] = (short)f2bf(b.y); o[6] = (short)f2bf(b.z); o[7] = (short)f2bf(b.w);
        *(short8*)(dst + i) = o;
    }
}

// ---------------------------------------------------------------------------
// bf16 GEMM: out = Xb @ Wb^T (+bias). 128x128 tile, BK=64, global_load_lds,
// XOR-swizzled LDS (conflict-free frag reads). XCD swizzle: XCD k owns
// row-groups g=k*12..k*12+11, all 8 n-tiles each.
// z=0: Q*(0.125*log2e) -> qh; z=1: K -> kh[n][h][t][d]; z=2: V -> vt[n][h][d][t].
// ---------------------------------------------------------------------------
__global__ __launch_bounds__(256) void proj_kernel(
    const u16* __restrict__ xb, const u16* __restrict__ wb,
    const float* __restrict__ bq, const float* __restrict__ bk, const float* __restrict__ bv,
    u16* __restrict__ qh, u16* __restrict__ kh, u16* __restrict__ vt)
{
    const int f = blockIdx.x;
    const int xcd = f & 7, jj = f >> 3;          // jj 0..95
    const int g  = xcd * 12 + (jj >> 3);         // row-group 0..95 (z*32+y)
    const int nx = jj & 7;                       // n-tile 0..7
    const int z  = g >> 5, y = g & 31;

    const u16* A  = xb + (size_t)z * 4194304;
    const u16* B  = wb + (size_t)z * 1048576;
    const float* Bp = (z == 0) ? bq : (z == 1) ? bk : bv;
    u16* dst        = (z == 0) ? qh : (z == 1) ? kh : vt;

    const int m0 = y * 128;
    const int n0 = nx * 128;
    const int tid  = threadIdx.x;
    const int wave = tid >> 6, lane = tid & 63;
    const int quad = lane >> 4, l15 = lane & 15;
    const int waveM = wave >> 1, waveN = wave & 1;
    const int sw = l15 & 7;                      // read-side swizzle key (row&7)

    __shared__ __align__(16) u16 smem[2 * 128 * 64];
    u16* As = smem;
    u16* Bs = smem + 128 * 64;

    floatx4 acc[4][4];
    for (int a = 0; a < 4; a++)
        for (int b = 0; b < 4; b++)
            acc[a][b] = floatx4{0.f, 0.f, 0.f, 0.f};

    const int lrow = lane >> 3;                  // 0..7 within 8-row slab
    const int gcol = ((lane & 7) ^ lrow) * 8;    // XOR-swizzled source chunk

    for (int k0 = 0; k0 < KDIM; k0 += 64) {
        for (int j = 0; j < 4; j++) {
            int r8 = wave * 32 + j * 8;
            gll16(A + (size_t)(m0 + r8 + lrow) * KDIM + k0 + gcol, &As[r8 * 64]);
        }
        for (int j = 0; j < 4; j++) {
            int r8 = wave * 32 + j * 8;
            gll16(B + (size_t)(n0 + r8 + lrow) * KDIM + k0 + gcol, &Bs[r8 * 64]);
        }
        __syncthreads();

        for (int ks = 0; ks < 2; ks++) {
            short8 af[4], bfg[4];
            for (int mb = 0; mb < 4; mb++)
                af[mb]  = *(const short8*)&As[(waveM * 64 + mb * 16 + l15) * 64 + ((ks * 4 + quad) ^ sw) * 8];
            for (int nb = 0; nb < 4; nb++)
                bfg[nb] = *(const short8*)&Bs[(waveN * 64 + nb * 16 + l15) * 64 + ((ks * 4 + quad) ^ sw) * 8];
            for (int mb = 0; mb < 4; mb++)
                for (int nb = 0; nb < 4; nb++)
                    acc[mb][nb] = __builtin_amdgcn_mfma_f32_16x16x32_bf16(af[mb], bfg[nb], acc[mb][nb], 0, 0, 0);
        }
        __syncthreads();
    }

    if (z != 2) {
        const int row0 = m0 + waveM * 64;
        const int col0 = n0 + waveN * 64;
        // z=0: fold 1/sqrt(d) * log2(e) so softmax uses bare exp2
        const float scale = (z == 0) ? 0.125f * 1.44269504f : 1.0f;
        for (int nb = 0; nb < 4; nb++) {
            int col = col0 + nb * 16 + l15;
            float bias = Bp[col];
            int hh = col >> 6, dd = col & 63;
            for (int mb = 0; mb < 4; mb++) {
                for (int r = 0; r < 4; r++) {
                    int row = row0 + mb * 16 + quad * 4 + r;   // C/D: row = quad*4+reg
                    int nn = row >> 11, ss = row & 2047;
                    dst[((size_t)(nn * HEADS + hh) * SEQ + ss) * DH + dd] =
                        f2bf((acc[mb][nb][r] + bias) * scale);
                }
            }
        }
    } else {
        // V^T [n][h][d][t]: transpose 64-col half-tiles through LDS, coalesced stores
        const int nn  = m0 >> 11;
        const int ss0 = m0 & 2047;
        for (int p = 0; p < 2; p++) {
            if (waveN == p) {
                for (int nb = 0; nb < 4; nb++) {
                    int col_l = nb * 16 + l15;                   // d within head, 0..63
                    float bias = Bp[n0 + p * 64 + col_l];
                    for (int mb = 0; mb < 4; mb++) {
                        short4v pk;
                        for (int r = 0; r < 4; r++)
                            pk[r] = (short)f2bf(acc[mb][nb][r] + bias);
                        *(short4v*)&smem[col_l * 136 + waveM * 64 + mb * 16 + quad * 4] = pk;
                    }
                }
            }
            __syncthreads();
            const int hh = (n0 >> 6) + p;
            u16* drow = dst + ((size_t)(nn * HEADS + hh) * DH) * SEQ + ss0;
            for (int c2 = tid; c2 < 1024; c2 += 256) {
                int dl = c2 >> 4, tc = (c2 & 15) * 8;
                short8 vv = *(const short8*)&smem[dl * 136 + tc];
                *(short8*)(drow + (size_t)dl * SEQ + tc) = vv;
            }
            __syncthreads();
        }
    }
}

// ---------------------------------------------------------------------------
// vmean[(n*H+h)*D + d] = mean over t of projected V (fallback for fully-masked rows)
// ---------------------------------------------------------------------------
__global__ __launch_bounds__(256) void vmean_kernel(const u16* __restrict__ vt,
                                                    float* __restrict__ vmean)
{
    const int row = blockIdx.x;                // (n*H + h)*D + d
    const u16* p = vt + (size_t)row * SEQ;
    const int tid = threadIdx.x;
    float s = 0.f;
    for (int i = tid; i < SEQ; i += 256) s += bf2f(p[i]);
    __shared__ float red[256];
    red[tid] = s;
    __syncthreads();
    for (int st = 128; st > 0; st >>= 1) {
        if (tid < st) red[tid] += red[tid + st];
        __syncthreads();
    }
    if (tid == 0) vmean[row] = red[0] * (1.f / (float)SEQ);
}

// ---------------------------------------------------------------------------
// Attention partials. Grid 1024: (xcd, nh-group, pr, sp). Without max-
// subtraction, partial (O,l) over disjoint t-sets are ADDITIVE -> block
// (nh, pr, sp) handles t-tiles tb = sp, sp+2, ... of the complementary pair
// (pr, 31-pr): 16/17 iters each, balanced, 1024 co-resident blocks (4/CU,
// 16 waves/CU; LDS 34 KB). K double-buffered, V single-buffered (2nd barrier,
// V load has the QK+exp phase as slack). Writes un-normalized partial O fp32
// + l to po/pl; merge_kernel normalizes. P packed via v_perm (trunc bf16).
// ---------------------------------------------------------------------------
__global__ __launch_bounds__(256, 4) void attn_kernel(
    const u16* __restrict__ qh, const u16* __restrict__ kh, const u16* __restrict__ vt,
    const int* __restrict__ pad, float* __restrict__ po, float* __restrict__ pl)
{
    const int f = blockIdx.x;                  // 0..1023
    const int xcd = f & 7, jj = f >> 3;        // jj 0..127
    const int nh = xcd * 4 + (jj >> 5);        // 4 heads per XCD (K/V L2-resident)
    const int rem = jj & 31;
    const int pr = rem >> 1, sp = rem & 1;     // pair index, t-parity split
    const int n = nh >> 4;
    const int tid  = threadIdx.x;
    const int wave = tid >> 6, lane = tid & 63;
    const int quad = lane >> 4, l15 = lane & 15;
    const int sw = l15 & 7;                    // frag-read swizzle key

    __shared__ __align__(16) u16 Ks[2][64 * 64];   // [t][d], XOR-swizzled, dbuf
    __shared__ __align__(16) u16 Vs[64 * 64];      // [d][t], XOR-swizzled, single
    __shared__ __align__(16) u16 Ps[64 * 72];      // P [s][t], wave-private rows
    __shared__ u64 padb[32];

    {   // pad bitmask via wave ballots
        const int* pp = pad + n * SEQ;
        for (int i = 0; i < 8; i++) {
            int seg = wave * 8 + i;
            u64 m = __ballot(pp[seg * 64 + lane] != 0);
            if (lane == 0) padb[seg] = m;
        }
    }

    const u16* qbase = qh + (size_t)nh * SEQ * DH;
    const u16* kbase = kh + (size_t)nh * SEQ * DH;
    const u16* vbase = vt + (size_t)nh * DH * SEQ;

    short8 ones;
    for (int i = 0; i < 8; i++) ones[i] = (short)0x3F80;   // bf16(1.0)

    const int lrow = lane >> 3;                 // 0..7 within 8-row slab
    const int gcol = ((lane & 7) ^ lrow) * 8;   // XOR-swizzled source chunk

    float* pobase = po + (size_t)(sp * 2 * HEADS + nh) * SEQ * DH;
    float* plbase = pl + (size_t)(sp * 2 * HEADS + nh) * SEQ;

    for (int half = 0; half < 2; half++) {
        const int sb = half ? (31 - pr) : pr;
        const int s0 = sb * 64;
        const int count = (sb >= sp) ? ((sb - sp) >> 1) + 1 : 0;
        const int srow = s0 + wave * 16 + l15;

        short8 qf[2];
        for (int ks = 0; ks < 2; ks++)
            qf[ks] = *(const short8*)(qbase + (size_t)srow * DH + ks * 32 + quad * 8);

        floatx4 oacc[4], lacc;
        for (int nd = 0; nd < 4; nd++) oacc[nd] = floatx4{0.f, 0.f, 0.f, 0.f};
        lacc = floatx4{0.f, 0.f, 0.f, 0.f};

        __syncthreads();   // LDS reuse across halves; padb visible (half 0)

        if (count > 0) {   // stage first K tile into Ks[0]
            for (int j = 0; j < 2; j++) {
                int r8 = wave * 16 + j * 8;
                gll16(kbase + (size_t)(sp * 64 + r8 + lrow) * DH + gcol, &Ks[0][r8 * 64]);
            }
        }

        for (int i = 0; i < count; i++) {
            const int tb = sp + 2 * i;
            const int t0 = tb * 64;
            const int cur = i & 1;
            __syncthreads();       // A: drains K[tb] gll16; Vs free (prev PV done)

            // V[tb] async into Vs (consumed after barrier B; slack = QK+exp phase)
            for (int j = 0; j < 2; j++) {
                int r8 = wave * 16 + j * 8;
                gll16(vbase + (size_t)(r8 + lrow) * SEQ + t0 + gcol, &Vs[r8 * 64]);
            }
            if (i + 1 < count) {   // K[tb+2] async into other K buffer
                for (int j = 0; j < 2; j++) {
                    int r8 = wave * 16 + j * 8;
                    gll16(kbase + (size_t)(t0 + 128 + r8 + lrow) * DH + gcol, &Ks[1 - cur][r8 * 64]);
                }
            }

            const u64 w = padb[tb];
            const bool diag = (tb == sb);

            // S^T = K Q^T : D[m=t][n=s]; lane r-quad consecutive in t
            floatx4 sc[4];
            for (int nb = 0; nb < 4; nb++) sc[nb] = floatx4{0.f, 0.f, 0.f, 0.f};
            for (int ks = 0; ks < 2; ks++)
                for (int nb = 0; nb < 4; nb++) {
                    short8 kf = *(const short8*)&Ks[cur][(nb * 16 + l15) * 64 + ((ks * 4 + quad) ^ sw) * 8];
                    sc[nb] = __builtin_amdgcn_mfma_f32_16x16x32_bf16(kf, qf[ks], sc[nb], 0, 0, 0);
                }

            // mask + exp2 + perm-packed 8B write into Ps[s][t]
            for (int nb = 0; nb < 4; nb++) {
                float p[4];
                for (int r = 0; r < 4; r++) {
                    int sh = nb * 16 + quad * 4 + r;        // t - t0
                    bool ok = ((w >> sh) & 1ull) != 0;
                    if (diag) ok = ok && (t0 + sh <= srow);
                    p[r] = ok ? __builtin_amdgcn_exp2f(sc[nb][r]) : 0.f;
                }
                uint2 pk;
                pk.x = pack_bf16_trunc(p[0], p[1]);
                pk.y = pack_bf16_trunc(p[2], p[3]);
                *(uint2*)&Ps[(wave * 16 + l15) * 72 + nb * 16 + quad * 4] = pk;
            }
            asm volatile("s_waitcnt lgkmcnt(0)" ::: "memory");   // wave-local Ps RAW
            __syncthreads();       // B: drains V[tb] (and K[tb+2]) gll16s

            // O += P V ; l += P @ ones
            for (int ks = 0; ks < 2; ks++) {
                short8 pa = *(const short8*)&Ps[(wave * 16 + l15) * 72 + ks * 32 + quad * 8];
                for (int nd = 0; nd < 4; nd++) {
                    short8 vb = *(const short8*)&Vs[(nd * 16 + l15) * 64 + ((ks * 4 + quad) ^ sw) * 8];
                    oacc[nd] = __builtin_amdgcn_mfma_f32_16x16x32_bf16(pa, vb, oacc[nd], 0, 0, 0);
                }
                lacc = __builtin_amdgcn_mfma_f32_16x16x32_bf16(pa, ones, lacc, 0, 0, 0);
            }
        }

        // epilogue: write un-normalized partials (zeros when count==0)
        for (int r = 0; r < 4; r++) {
            int s = s0 + wave * 16 + quad * 4 + r;
            float* orow = pobase + (size_t)s * DH;
            for (int nd = 0; nd < 4; nd++) orow[nd * 16 + l15] = oacc[nd][r];
            if (l15 == 0) plbase[s] = lacc[r];   // l is col-invariant in C-layout
        }
    }
}

// ---------------------------------------------------------------------------
// merge: out = (poA+poB)/(lA+lB); fully-masked rows (l==0) -> vmean.
// One block per (n,s) row: coalesced float4 reads/writes.
// ---------------------------------------------------------------------------
__global__ __launch_bounds__(256) void merge_kernel(
    const float* __restrict__ po, const float* __restrict__ pl,
    const float* __restrict__ vmean, float* __restrict__ out)
{
    const int ns = blockIdx.x;                 // (n,s): 4096
    const int n = ns >> 11, s = ns & 2047;
    const int c = threadIdx.x;
    const int h = c >> 4, d4 = (c & 15) * 4;
    const int nh = n * HEADS + h;
    const size_t PSTRIDE  = (size_t)2 * HEADS * SEQ * DH;  // floats per partial
    const size_t LSTRIDE  = (size_t)2 * HEADS * SEQ;
    const size_t idx = ((size_t)nh * SEQ + s) * DH + d4;

    float4 a = *(const float4*)(po + idx);
    float4 b = *(const float4*)(po + PSTRIDE + idx);
    float l = pl[(size_t)nh * SEQ + s] + pl[LSTRIDE + (size_t)nh * SEQ + s];
    float4 o;
    if (l > 0.f) {
        float inv = 1.f / l;
        o.x = (a.x + b.x) * inv; o.y = (a.y + b.y) * inv;
        o.z = (a.z + b.z) * inv; o.w = (a.w + b.w) * inv;
    } else {
        o = *(const float4*)(vmean + nh * DH + d4);
    }
    *(float4*)(out + ((size_t)(n * SEQ + s)) * EMB + c * 4) = o;
}

extern "C" void kernel_launch(void* const* d_in, const int* in_sizes, int n_in,
                              void* d_out, int out_size, void* d_ws, size_t ws_size,
                              hipStream_t stream)
{
    const float* qin = (const float*)d_in[0];
    const float* kin = (const float*)d_in[1];
    const float* vin = (const float*)d_in[2];
    const int*   pad = (const int*)d_in[3];
    // d_in[4] = subsq_mask (tril) — implemented analytically as t <= s
    const float* Wq = (const float*)d_in[5];
    const float* bq = (const float*)d_in[6];
    const float* Wk = (const float*)d_in[7];
    const float* bk = (const float*)d_in[8];
    const float* Wv = (const float*)d_in[9];
    const float* bv = (const float*)d_in[10];
    float* out = (float*)d_out;

    const size_t per = (size_t)NBAT * HEADS * SEQ * DH;  // 4M elements
    u16* qh = (u16*)d_ws;
    u16* kh = qh + per;
    u16* vt = kh + per;
    float* vmean = (float*)(vt + per);                   // 2048 floats
    char* scratch = (char*)(vmean + 2048);
    u16* xb = (u16*)scratch;                             // 3 x 4M bf16 (24 MB)
    u16* wb = xb + 3 * per;                              // 3 x 1M bf16 (6 MB)
    // po/pl OVERLAY xb/wb: xb/wb are dead after proj; attn writes po afterward
    float* po = (float*)scratch;                         // 2 x 16.8 MB fp32 partial O
    float* pl = po + (size_t)2 * HEADS * NBAT * SEQ * DH / 1 * 1;  // after po
    pl = po + (size_t)2 * 2 * HEADS * SEQ * DH;          // 2 partials x 32 nh x S x D

    cvt_kernel<<<dim3(512, 6), 256, 0, stream>>>(qin, kin, vin, Wq, Wk, Wv, xb, wb);
    proj_kernel<<<dim3(768), 256, 0, stream>>>(xb, wb, bq, bk, bv, qh, kh, vt);
    vmean_kernel<<<dim3(NBAT * HEADS * DH), 256, 0, stream>>>(vt, vmean);
    attn_kernel<<<dim3(1024), 256, 0, stream>>>(qh, kh, vt, pad, po, pl);
    merge_kernel<<<dim3(NBAT * SEQ), 256, 0, stream>>>(po, pl, vmean, out);
}

// Round 9
// 225.995 us; speedup vs baseline: 1.0098x; 1.0098x over previous
//
#include <hip/hip_runtime.h>

#define HEADS 16
#define DH    64
#define EMB   1024
#define NBAT  2
#define SEQ   2048
#define KDIM  1024
#define NROW  (NBAT * SEQ)     // 4096 rows in projection GEMM

typedef __attribute__((ext_vector_type(8))) short short8;   // 8 bf16 MFMA A/B frag
typedef __attribute__((ext_vector_type(4))) short short4v;  // 4 bf16 (8B packed)
typedef __attribute__((ext_vector_type(4))) float floatx4;  // MFMA C/D frag
typedef unsigned short u16;
typedef unsigned int   u32;
typedef unsigned long long u64;

__device__ __forceinline__ u16 f2bf(float x) {          // fp32 -> bf16 RNE
    u32 u = __builtin_bit_cast(u32, x);
    u += 0x7fffu + ((u >> 16) & 1u);
    return (u16)(u >> 16);
}
__device__ __forceinline__ float bf2f(u16 v) {
    return __builtin_bit_cast(float, ((u32)v) << 16);
}
// pack two fp32 -> two bf16 (truncation) in ONE v_perm_b32
__device__ __forceinline__ u32 pack_bf16_trunc(float lo, float hi) {
    return __builtin_amdgcn_perm(__builtin_bit_cast(u32, hi),
                                 __builtin_bit_cast(u32, lo), 0x07060302u);
}

// async global->LDS, 16B per lane; LDS dest is wave-uniform base + lane*16
__device__ __forceinline__ void gll16(const u16* g, u16* l) {
    __builtin_amdgcn_global_load_lds((const __attribute__((address_space(1))) u32*)g,
                                     (__attribute__((address_space(3))) u32*)l, 16, 0, 0);
}

// ---------------------------------------------------------------------------
// fp32 -> bf16 pre-convert of X (q,k,v: 4M elems each) and W (wq,wk,wv: 1M each)
// ---------------------------------------------------------------------------
__global__ __launch_bounds__(256) void cvt_kernel(
    const float* __restrict__ q, const float* __restrict__ k, const float* __restrict__ v,
    const float* __restrict__ wq, const float* __restrict__ wk, const float* __restrict__ wv,
    u16* __restrict__ xb, u16* __restrict__ wb)
{
    const int z = blockIdx.y;
    const float* src; u16* dst; int n;
    if (z < 3) { src = (z == 0) ? q : (z == 1) ? k : v;     dst = xb + (size_t)z * 4194304;       n = 4194304; }
    else       { src = (z == 3) ? wq : (z == 4) ? wk : wv;  dst = wb + (size_t)(z - 3) * 1048576; n = 1048576; }
    for (int i = (blockIdx.x * 256 + threadIdx.x) * 8; i < n; i += 512 * 256 * 8) {
        float4 a = *(const float4*)(src + i);
        float4 b = *(const float4*)(src + i + 4);
        short8 o;
        o[0] = (short)f2bf(a.x); o[1] = (short)f2bf(a.y); o[2] = (short)f2bf(a.z); o[3] = (short)f2bf(a.w);
        o[4] = (short)f2bf(b.x); o[5] = (short)f2bf(b.y); o[6] = (short)f2bf(b.z); o[7] = (short)f2bf(b.w);
        *(short8*)(dst + i) = o;
    }
}

// ---------------------------------------------------------------------------
// bf16 GEMM: out = Xb @ Wb^T (+bias). 128x128 tile, BK=64, global_load_lds,
// XOR-swizzled LDS (conflict-free frag reads). XCD swizzle: XCD k owns
// row-groups g=k*12..k*12+11, all 8 n-tiles each.
// z=0: Q*(0.125*log2e) -> qh; z=1: K -> kh[n][h][t][d]; z=2: V -> vt[n][h][d][t].
// ---------------------------------------------------------------------------
__global__ __launch_bounds__(256) void proj_kernel(
    const u16* __restrict__ xb, const u16* __restrict__ wb,
    const float* __restrict__ bq, const float* __restrict__ bk, const float* __restrict__ bv,
    u16* __restrict__ qh, u16* __restrict__ kh, u16* __restrict__ vt)
{
    const int f = blockIdx.x;
    const int xcd = f & 7, jj = f >> 3;          // jj 0..95
    const int g  = xcd * 12 + (jj >> 3);         // row-group 0..95 (z*32+y)
    const int nx = jj & 7;                       // n-tile 0..7
    const int z  = g >> 5, y = g & 31;

    const u16* A  = xb + (size_t)z * 4194304;
    const u16* B  = wb + (size_t)z * 1048576;
    const float* Bp = (z == 0) ? bq : (z == 1) ? bk : bv;
    u16* dst        = (z == 0) ? qh : (z == 1) ? kh : vt;

    const int m0 = y * 128;
    const int n0 = nx * 128;
    const int tid  = threadIdx.x;
    const int wave = tid >> 6, lane = tid & 63;
    const int quad = lane >> 4, l15 = lane & 15;
    const int waveM = wave >> 1, waveN = wave & 1;
    const int sw = l15 & 7;                      // read-side swizzle key (row&7)

    __shared__ __align__(16) u16 smem[2 * 128 * 64];
    u16* As = smem;
    u16* Bs = smem + 128 * 64;

    floatx4 acc[4][4];
    for (int a = 0; a < 4; a++)
        for (int b = 0; b < 4; b++)
            acc[a][b] = floatx4{0.f, 0.f, 0.f, 0.f};

    const int lrow = lane >> 3;                  // 0..7 within 8-row slab
    const int gcol = ((lane & 7) ^ lrow) * 8;    // XOR-swizzled source chunk

    for (int k0 = 0; k0 < KDIM; k0 += 64) {
        for (int j = 0; j < 4; j++) {
            int r8 = wave * 32 + j * 8;
            gll16(A + (size_t)(m0 + r8 + lrow) * KDIM + k0 + gcol, &As[r8 * 64]);
        }
        for (int j = 0; j < 4; j++) {
            int r8 = wave * 32 + j * 8;
            gll16(B + (size_t)(n0 + r8 + lrow) * KDIM + k0 + gcol, &Bs[r8 * 64]);
        }
        __syncthreads();

        for (int ks = 0; ks < 2; ks++) {
            short8 af[4], bfg[4];
            for (int mb = 0; mb < 4; mb++)
                af[mb]  = *(const short8*)&As[(waveM * 64 + mb * 16 + l15) * 64 + ((ks * 4 + quad) ^ sw) * 8];
            for (int nb = 0; nb < 4; nb++)
                bfg[nb] = *(const short8*)&Bs[(waveN * 64 + nb * 16 + l15) * 64 + ((ks * 4 + quad) ^ sw) * 8];
            for (int mb = 0; mb < 4; mb++)
                for (int nb = 0; nb < 4; nb++)
                    acc[mb][nb] = __builtin_amdgcn_mfma_f32_16x16x32_bf16(af[mb], bfg[nb], acc[mb][nb], 0, 0, 0);
        }
        __syncthreads();
    }

    if (z != 2) {
        const int row0 = m0 + waveM * 64;
        const int col0 = n0 + waveN * 64;
        // z=0: fold 1/sqrt(d) * log2(e) so softmax uses bare exp2
        const float scale = (z == 0) ? 0.125f * 1.44269504f : 1.0f;
        for (int nb = 0; nb < 4; nb++) {
            int col = col0 + nb * 16 + l15;
            float bias = Bp[col];
            int hh = col >> 6, dd = col & 63;
            for (int mb = 0; mb < 4; mb++) {
                for (int r = 0; r < 4; r++) {
                    int row = row0 + mb * 16 + quad * 4 + r;   // C/D: row = quad*4+reg
                    int nn = row >> 11, ss = row & 2047;
                    dst[((size_t)(nn * HEADS + hh) * SEQ + ss) * DH + dd] =
                        f2bf((acc[mb][nb][r] + bias) * scale);
                }
            }
        }
    } else {
        // V^T [n][h][d][t]: transpose 64-col half-tiles through LDS, coalesced stores
        const int nn  = m0 >> 11;
        const int ss0 = m0 & 2047;
        for (int p = 0; p < 2; p++) {
            if (waveN == p) {
                for (int nb = 0; nb < 4; nb++) {
                    int col_l = nb * 16 + l15;                   // d within head, 0..63
                    float bias = Bp[n0 + p * 64 + col_l];
                    for (int mb = 0; mb < 4; mb++) {
                        short4v pk;
                        for (int r = 0; r < 4; r++)
                            pk[r] = (short)f2bf(acc[mb][nb][r] + bias);
                        *(short4v*)&smem[col_l * 136 + waveM * 64 + mb * 16 + quad * 4] = pk;
                    }
                }
            }
            __syncthreads();
            const int hh = (n0 >> 6) + p;
            u16* drow = dst + ((size_t)(nn * HEADS + hh) * DH) * SEQ + ss0;
            for (int c2 = tid; c2 < 1024; c2 += 256) {
                int dl = c2 >> 4, tc = (c2 & 15) * 8;
                short8 vv = *(const short8*)&smem[dl * 136 + tc];
                *(short8*)(drow + (size_t)dl * SEQ + tc) = vv;
            }
            __syncthreads();
        }
    }
}

// ---------------------------------------------------------------------------
// vmean[(n*H+h)*D + d] = mean over t of projected V (fallback for fully-masked rows)
// ---------------------------------------------------------------------------
__global__ __launch_bounds__(256) void vmean_kernel(const u16* __restrict__ vt,
                                                    float* __restrict__ vmean)
{
    const int row = blockIdx.x;                // (n*H + h)*D + d
    const u16* p = vt + (size_t)row * SEQ;
    const int tid = threadIdx.x;
    float s = 0.f;
    for (int i = tid; i < SEQ; i += 256) s += bf2f(p[i]);
    __shared__ float red[256];
    red[tid] = s;
    __syncthreads();
    for (int st = 128; st > 0; st >>= 1) {
        if (tid < st) red[tid] += red[tid + st];
        __syncthreads();
    }
    if (tid == 0) vmean[row] = red[0] * (1.f / (float)SEQ);
}

// ---------------------------------------------------------------------------
// Attention, 512 threads = TWO 4-wave groups split by t-tile parity.
// Grid 512: (xcd, nh, pr); block processes Q-tile pair (pr, 31-pr).
// Group g handles t-tiles tb ≡ g (mod 2) of each half: 16/17 iters, balanced.
// Additive (O,l) partials (no max-subtraction) merged IN-BLOCK via LDS at the
// end of each half (group1 dumps into its Ks/Ps areas; group0 adds, divides,
// writes fp32 out; l==0 rows -> vmean). No merge kernel, no partial traffic.
// Loop body is the r6-VERIFIED ordering: V[tb] + K-next issued right after
// barrier A, drained at barrier B (r7/r8's "K after B" failed twice — the
// gll16 must be drained at the NEXT barrier, not 2 barriers later).
// 'act' is wave-uniform so block-wide barriers are safe; idle group still
// executes every barrier. LDS 66.3KB -> 2 blocks/CU (16 waves/CU).
// ---------------------------------------------------------------------------
__global__ __launch_bounds__(512, 4) void attn_kernel(
    const u16* __restrict__ qh, const u16* __restrict__ kh, const u16* __restrict__ vt,
    const int* __restrict__ pad, const float* __restrict__ vmean,
    float* __restrict__ out)
{
    const int f = blockIdx.x;                  // 0..511
    const int xcd = f & 7, jj = f >> 3;        // jj 0..63
    const int nh = xcd * 4 + (jj >> 4);        // 4 heads per XCD (K/V L2-resident)
    const int pr = jj & 15;
    const int n = nh >> 4, h = nh & 15;
    const int tid  = threadIdx.x;
    const int wave = tid >> 6;                 // 0..7
    const int grp  = wave >> 2;                // t-parity group 0/1
    const int w4   = wave & 3;                 // wave within group
    const int lane = tid & 63;
    const int quad = lane >> 4, l15 = lane & 15;
    const int sw = l15 & 7;                    // frag-read swizzle key

    __shared__ __align__(16) u16 Ks[2][2][64 * 64];  // [grp][dbuf][t][d] 32KB
    __shared__ __align__(16) u16 Vs[2][64 * 64];     // [grp][d][t]       16KB
    __shared__ __align__(16) u16 Ps[2][64 * 72];     // [grp] P[s][t]     18KB
    __shared__ u64 padb[32];

    {   // pad bitmask via wave ballots (8 waves x 4 segs = 32)
        const int* pp = pad + n * SEQ;
        for (int i = 0; i < 4; i++) {
            int seg = wave * 4 + i;
            u64 m = __ballot(pp[seg * 64 + lane] != 0);
            if (lane == 0) padb[seg] = m;
        }
    }

    const u16* qbase = qh + (size_t)nh * SEQ * DH;
    const u16* kbase = kh + (size_t)nh * SEQ * DH;
    const u16* vbase = vt + (size_t)nh * DH * SEQ;

    short8 ones;
    for (int i = 0; i < 8; i++) ones[i] = (short)0x3F80;   // bf16(1.0)
    float vm[4];
    for (int nd = 0; nd < 4; nd++) vm[nd] = vmean[nh * DH + nd * 16 + l15];

    const int lrow = lane >> 3;                 // 0..7 within 8-row slab
    const int gcol = ((lane & 7) ^ lrow) * 8;   // XOR-swizzled source chunk
    const floatx4 zero4 = floatx4{0.f, 0.f, 0.f, 0.f};

    // in-block merge buffers (alias group1's Ks (16KB) and Ps areas)
    float* odump = (float*)&Ks[1][0][0];        // 64 x 64 fp32 = 16KB
    float* ldump = (float*)&Ps[1][0];           // 64 fp32

    for (int half = 0; half < 2; half++) {
        const int sb = half ? (31 - pr) : pr;
        const int s0 = sb * 64;
        const int cnt  = (sb >= grp) ? ((sb - grp) >> 1) + 1 : 0;  // my tiles
        const int maxc = (sb >> 1) + 1;                             // = cnt(grp0)
        const int srow = s0 + w4 * 16 + l15;

        short8 qf[2];
        for (int ks = 0; ks < 2; ks++)
            qf[ks] = *(const short8*)(qbase + (size_t)srow * DH + ks * 32 + quad * 8);

        floatx4 oacc[4], lacc;
        for (int nd = 0; nd < 4; nd++) oacc[nd] = zero4;
        lacc = zero4;

        __syncthreads();   // top: prior half's epilogue LDS reads done; padb visible

        if (cnt > 0) {     // stage first K tile (tb = grp) into Ks[grp][0]
            for (int j = 0; j < 2; j++) {
                int r8 = w4 * 16 + j * 8;
                gll16(kbase + (size_t)(grp * 64 + r8 + lrow) * DH + gcol, &Ks[grp][0][r8 * 64]);
            }
        }

        for (int i = 0; i < maxc; i++) {
            const bool act = (i < cnt);         // wave-uniform
            const int tb = grp + 2 * i;
            const int t0 = tb * 64;
            const int cur = i & 1;
            __syncthreads();       // A: drains my K[tb]; Vs[grp] free (prev PV done)

            if (act) {
                // V[tb] + K[tb+2] issued now, BOTH drained at barrier B (r6-verified)
                for (int j = 0; j < 2; j++) {
                    int r8 = w4 * 16 + j * 8;
                    gll16(vbase + (size_t)(r8 + lrow) * SEQ + t0 + gcol, &Vs[grp][r8 * 64]);
                }
                if (i + 1 < cnt) {
                    for (int j = 0; j < 2; j++) {
                        int r8 = w4 * 16 + j * 8;
                        gll16(kbase + (size_t)(t0 + 128 + r8 + lrow) * DH + gcol, &Ks[grp][1 - cur][r8 * 64]);
                    }
                }

                const u64 w = padb[tb];
                const bool diag = (tb == sb);

                // S^T = K Q^T : D[m=t][n=s]; lane r-quad consecutive in t
                floatx4 sc[4];
                for (int nb = 0; nb < 4; nb++) sc[nb] = zero4;
                for (int ks = 0; ks < 2; ks++)
                    for (int nb = 0; nb < 4; nb++) {
                        short8 kf = *(const short8*)&Ks[grp][cur][(nb * 16 + l15) * 64 + ((ks * 4 + quad) ^ sw) * 8];
                        sc[nb] = __builtin_amdgcn_mfma_f32_16x16x32_bf16(kf, qf[ks], sc[nb], 0, 0, 0);
                    }

                // pad+causal mask + exp2 + trunc-packed 8B write into Ps[s][t]
                for (int nb = 0; nb < 4; nb++) {
                    float p[4];
                    for (int r = 0; r < 4; r++) {
                        int sh = nb * 16 + quad * 4 + r;        // t - t0
                        bool ok = ((w >> sh) & 1ull) != 0;
                        if (diag) ok = ok && (t0 + sh <= srow);
                        p[r] = ok ? __builtin_amdgcn_exp2f(sc[nb][r]) : 0.f;
                    }
                    uint2 pk;
                    pk.x = pack_bf16_trunc(p[0], p[1]);
                    pk.y = pack_bf16_trunc(p[2], p[3]);
                    *(uint2*)&Ps[grp][(w4 * 16 + l15) * 72 + nb * 16 + quad * 4] = pk;
                }
                asm volatile("s_waitcnt lgkmcnt(0)" ::: "memory");   // wave-local Ps RAW
            }
            __syncthreads();       // B: drains V[tb] + K[tb+2] gll16s

            if (act) {
                // O += P V ; l += P @ ones
                for (int ks = 0; ks < 2; ks++) {
                    short8 pa = *(const short8*)&Ps[grp][(w4 * 16 + l15) * 72 + ks * 32 + quad * 8];
                    for (int nd = 0; nd < 4; nd++) {
                        short8 vb = *(const short8*)&Vs[grp][(nd * 16 + l15) * 64 + ((ks * 4 + quad) ^ sw) * 8];
                        oacc[nd] = __builtin_amdgcn_mfma_f32_16x16x32_bf16(pa, vb, oacc[nd], 0, 0, 0);
                    }
                    lacc = __builtin_amdgcn_mfma_f32_16x16x32_bf16(pa, ones, lacc, 0, 0, 0);
                }
            }
        }

        // in-block merge of the two parity partials
        __syncthreads();           // C: all QK/PV LDS reads done; Ks[1]/Ps[1] reusable
        if (grp == 1) {
            for (int r = 0; r < 4; r++) {
                int sl = w4 * 16 + quad * 4 + r;
                for (int nd = 0; nd < 4; nd++)
                    odump[sl * 64 + nd * 16 + l15] = oacc[nd][r];
                if (l15 == 0) ldump[sl] = lacc[r];
            }
        }
        __syncthreads();           // D: dump visible
        if (grp == 0) {
            for (int r = 0; r < 4; r++) {
                int sl = w4 * 16 + quad * 4 + r;
                int s = s0 + sl;
                float l = lacc[r] + ldump[sl];
                float* orow = out + (size_t)(n * SEQ + s) * EMB + h * DH;
                if (l > 0.f) {
                    float inv = 1.f / l;
                    for (int nd = 0; nd < 4; nd++)
                        orow[nd * 16 + l15] = (oacc[nd][r] + odump[sl * 64 + nd * 16 + l15]) * inv;
                } else {
                    for (int nd = 0; nd < 4; nd++) orow[nd * 16 + l15] = vm[nd];
                }
            }
        }
    }
}

extern "C" void kernel_launch(void* const* d_in, const int* in_sizes, int n_in,
                              void* d_out, int out_size, void* d_ws, size_t ws_size,
                              hipStream_t stream)
{
    const float* qin = (const float*)d_in[0];
    const float* kin = (const float*)d_in[1];
    const float* vin = (const float*)d_in[2];
    const int*   pad = (const int*)d_in[3];
    // d_in[4] = subsq_mask (tril) — implemented analytically as t <= s
    const float* Wq = (const float*)d_in[5];
    const float* bq = (const float*)d_in[6];
    const float* Wk = (const float*)d_in[7];
    const float* bk = (const float*)d_in[8];
    const float* Wv = (const float*)d_in[9];
    const float* bv = (const float*)d_in[10];
    float* out = (float*)d_out;

    const size_t per = (size_t)NBAT * HEADS * SEQ * DH;  // 4M elements
    u16* qh = (u16*)d_ws;
    u16* kh = qh + per;
    u16* vt = kh + per;
    float* vmean = (float*)(vt + per);                   // 2048 floats
    u16* xb = (u16*)(vmean + 2048);                      // 3 x 4M bf16
    u16* wb = xb + 3 * per;                              // 3 x 1M bf16

    cvt_kernel<<<dim3(512, 6), 256, 0, stream>>>(qin, kin, vin, Wq, Wk, Wv, xb, wb);
    proj_kernel<<<dim3(768), 256, 0, stream>>>(xb, wb, bq, bk, bv, qh, kh, vt);
    vmean_kernel<<<dim3(NBAT * HEADS * DH), 256, 0, stream>>>(vt, vmean);
    attn_kernel<<<dim3(512), 512, 0, stream>>>(qh, kh, vt, pad, vmean, out);
}